// Round 13
// baseline (156.168 us; speedup 1.0000x reference)
//
#include <hip/hip_runtime.h>
#include <hip/hip_bf16.h>
#include <math.h>

// Problem constants
#define Bc 4
#define Nc 1024
#define Ec 1024
#define Hc 16
#define Dc 64
#define Mc 4096                    // B*N rows
#define OUT0_ELEMS 4194304         // B*H*N*D
#define ATTN_ELEMS 67108864ULL     // B*H*N*N floats
#define SCRATCH_OFF 58720256       // float offset into attn region for bf16 scratch
#define NTK 32                     // K-tiles (BK=32) in proj

typedef __attribute__((ext_vector_type(4))) float f32x4;
typedef __attribute__((ext_vector_type(16))) float f32x16;
typedef __attribute__((ext_vector_type(8))) short s16x8;

// Hardware bf16 convert (compiler pairs into v_cvt_pk_bf16_f32)
__device__ __forceinline__ short f2bf(float f) {
    union { __bf16 h; short s; } c; c.h = (__bf16)f; return c.s;
}

// async global->LDS, 16B per lane; LDS dest = wave-uniform base + lane*16
typedef const __attribute__((address_space(1))) char gch;
typedef __attribute__((address_space(3))) char lch;
__device__ __forceinline__ void gload16(const short* g, short* l) {
    __builtin_amdgcn_global_load_lds((gch*)g, (lch*)l, 16, 0, 0);
}

// ---------------------------------------------------------------------------
// fp32 -> bf16 pre-pass, W matrices ONLY (12 MB): X is now converted
// in-kernel inside proj's pipeline (A-operand reg-staging).
// ---------------------------------------------------------------------------
__global__ __launch_bounds__(256)
void cvt_kernel(const float* __restrict__ wq, const float* __restrict__ wk,
                const float* __restrict__ wv, short* __restrict__ dst)
{
    const int which = blockIdx.y;
    const float* src = (which == 0) ? wq : (which == 1) ? wk : wv;
    const size_t off = (size_t)which * 1048576;
    const size_t i = ((size_t)blockIdx.x * 256 + threadIdx.x) * 8;
    f32x4 a = *(const f32x4*)(src + i);
    f32x4 b = *(const f32x4*)(src + i + 4);
    s16x8 o;
    o[0] = f2bf(a[0]); o[1] = f2bf(a[1]); o[2] = f2bf(a[2]); o[3] = f2bf(a[3]);
    o[4] = f2bf(b[0]); o[5] = f2bf(b[1]); o[6] = f2bf(b[2]); o[7] = f2bf(b[3]);
    *(s16x8*)(dst + off + i) = o;
}

// ---------------------------------------------------------------------------
// Projection GEMM, round-13: A (X input) read as fp32 + reg-staged
// (cvt_pk + swizzled ds_write_b128) inside the counted-vmcnt pipeline;
// B (W) stays bf16 via global_load_lds with 3-buffer rotation.
// Per stage: 4 A-reg-loads + 2 B-gloads = 6 vmcnt entries; vmcnt(6) at
// iteration top retires stage t wholesale. A uses a SINGLE LDS buffer
// (written after barrier2 of t-1, read after barrier1 of t).
// LDS = 8 KB (A) + 24 KB (B) = 32 KB.
// ---------------------------------------------------------------------------
__global__ __launch_bounds__(256)
void proj_kernel(const float* __restrict__ xq, const float* __restrict__ xk,
                 const float* __restrict__ xv, const short* __restrict__ wall,
                 const float* __restrict__ bq, const float* __restrict__ bk,
                 const float* __restrict__ bv,
                 short* __restrict__ qws, short* __restrict__ kws,
                 float* __restrict__ vout)
{
    const int sel = blockIdx.z;
    const float* X = (sel == 0) ? xq : (sel == 1) ? xk : xv;
    const short* W = wall + (size_t)sel * 1048576;
    const float* bias = (sel == 0) ? bq : (sel == 1) ? bk : bv;

    __shared__ __align__(16) short lA[128 * 32];
    __shared__ __align__(16) short lB[3][128 * 32];

    const int t    = threadIdx.x;
    const int lane = t & 63;
    const int w    = t >> 6;
    const int wr   = w >> 1, wc = w & 1;      // 2x2 wave grid, 64x64 each
    const int li   = lane & 15, g = lane >> 4;
    const int bm   = blockIdx.x * 128;
    const int bn   = blockIdx.y * 128;

    // A staging: lane -> row w*32+(lane&31), 16-float half (lane>>5)
    const int arow = w * 32 + (lane & 31);
    const int ah   = lane >> 5;
    const float* Xs = X + (size_t)(bm + arow) * Ec + ah * 16;
    const int asw = (arow >> 1) & 3;
    short* wA0 = &lA[arow * 32 + (((ah * 2)     ^ asw) * 8)];
    short* wA1 = &lA[arow * 32 + (((ah * 2 + 1) ^ asw) * 8)];

    // B staging (R7 mapping): 16B chunk pre-swizzled global source
    const int sr = lane >> 2;
    const int c_ = lane & 3;

    f32x4 acc[4][4];
#pragma unroll
    for (int i = 0; i < 4; ++i)
#pragma unroll
        for (int j = 0; j < 4; ++j)
            acc[i][j] = (f32x4){0.f, 0.f, 0.f, 0.f};

    f32x4 eA0, eA1, eA2, eA3;   // even-parity A reg set
    f32x4 oA0, oA1, oA2, oA3;   // odd-parity A reg set

#define LOADA(q0, q1, q2, q3, kt)                                             \
    {                                                                         \
        const float* p = Xs + (kt) * 32;                                      \
        q0 = *(const f32x4*)(p);                                              \
        q1 = *(const f32x4*)(p + 4);                                          \
        q2 = *(const f32x4*)(p + 8);                                          \
        q3 = *(const f32x4*)(p + 12);                                         \
    }

#define STAGEB(buf, kt)                                                       \
    {                                                                         \
        const int kb = (kt) * 32;                                             \
        _Pragma("unroll")                                                     \
        for (int j = 0; j < 2; ++j) {                                         \
            const int row = w * 32 + j * 16 + sr;                             \
            const int cg  = (c_ ^ ((row >> 1) & 3)) * 8;                      \
            gload16(W + (size_t)(bn + row) * Ec + kb + cg,                    \
                    &lB[buf][(w * 32 + j * 16) * 32]);                        \
        }                                                                     \
    }

#define WRITEA(q0, q1, q2, q3)                                                \
    {                                                                         \
        s16x8 h0, h1;                                                         \
        _Pragma("unroll")                                                     \
        for (int i = 0; i < 4; ++i) {                                         \
            h0[i] = f2bf(q0[i]); h0[i + 4] = f2bf(q1[i]);                     \
            h1[i] = f2bf(q2[i]); h1[i + 4] = f2bf(q3[i]);                     \
        }                                                                     \
        *(s16x8*)wA0 = h0;                                                    \
        *(s16x8*)wA1 = h1;                                                    \
    }

#define COMPUTE(bufB)                                                         \
    {                                                                         \
        s16x8 aF[4], bF[4];                                                   \
        _Pragma("unroll")                                                     \
        for (int mt = 0; mt < 4; ++mt) {                                      \
            const int r = wr * 64 + mt * 16 + li;                             \
            aF[mt] = *(const s16x8*)&lA[r * 32 + ((g ^ ((r >> 1) & 3)) * 8)]; \
        }                                                                     \
        _Pragma("unroll")                                                     \
        for (int nt = 0; nt < 4; ++nt) {                                      \
            const int r = wc * 64 + nt * 16 + li;                             \
            bF[nt] = *(const s16x8*)&lB[bufB][r * 32 + ((g ^ ((r >> 1) & 3)) * 8)]; \
        }                                                                     \
        _Pragma("unroll")                                                     \
        for (int mt = 0; mt < 4; ++mt)                                        \
            _Pragma("unroll")                                                 \
            for (int nt = 0; nt < 4; ++nt)                                    \
                acc[mt][nt] = __builtin_amdgcn_mfma_f32_16x16x32_bf16(        \
                    aF[mt], bF[nt], acc[mt][nt], 0, 0, 0);                    \
    }

#define ITER(t_, q0, q1, q2, q3)                                              \
    {                                                                         \
        if ((t_) < NTK - 1)                                                   \
            asm volatile("s_waitcnt vmcnt(6)" ::: "memory");                  \
        else                                                                  \
            asm volatile("s_waitcnt vmcnt(0)" ::: "memory");                  \
        WRITEA(q0, q1, q2, q3);                                               \
        asm volatile("s_waitcnt lgkmcnt(0)" ::: "memory");                    \
        __builtin_amdgcn_s_barrier();                                         \
        COMPUTE((t_) % 3);                                                    \
        if ((t_) + 2 < NTK) {                                                 \
            LOADA(q0, q1, q2, q3, (t_) + 2);                                  \
            STAGEB(((t_) + 2) % 3, (t_) + 2);                                 \
        }                                                                     \
        __builtin_amdgcn_s_barrier();                                         \
    }

    // prologue: stages 0 and 1 in flight (12 vmcnt entries)
    LOADA(eA0, eA1, eA2, eA3, 0);
    STAGEB(0, 0);
    LOADA(oA0, oA1, oA2, oA3, 1);
    STAGEB(1, 1);

    for (int tt = 0; tt < NTK; tt += 2) {
        ITER(tt,     eA0, eA1, eA2, eA3);
        ITER(tt + 1, oA0, oA1, oA2, oA3);
    }
#undef ITER
#undef COMPUTE
#undef WRITEA
#undef STAGEB
#undef LOADA

    // ---- epilogue: bias add + head-split scatter ----
    short* dstBF = (sel == 0) ? qws : kws;
#pragma unroll
    for (int nt = 0; nt < 4; ++nt) {
        const int col = bn + wc * 64 + nt * 16 + li;
        const float bcol = bias[col];
        const int h = col >> 6, d = col & 63;
#pragma unroll
        for (int mt = 0; mt < 4; ++mt) {
#pragma unroll
            for (int r = 0; r < 4; ++r) {
                const int row = bm + wr * 64 + mt * 16 + g * 4 + r;
                const int bb = row >> 10, n = row & 1023;
                const size_t off = ((size_t)(bb * Hc + h) * Nc + n) * Dc + d;
                const float val = acc[mt][nt][r] + bcol;
                if (sel == 2)
                    vout[off] = val;
                else
                    dstBF[off] = f2bf(val);
            }
        }
    }
}

// ---------------------------------------------------------------------------
// Scores + softmax (R10 exact: 8 waves x 128 cols, no max pass, NT stores,
// XCD-clustered grid).
// ---------------------------------------------------------------------------
__global__ __launch_bounds__(512, 4)
void attn_kernel(const short* __restrict__ qws, const short* __restrict__ kws,
                 float* __restrict__ attnOut)
{
    const int bid = blockIdx.x;                 // 0..2047
    const int rb  = (bid >> 3) & 31;            // 32-row block
    const int bh  = ((bid & 7) << 3) | (bid >> 8);  // head: bid%8 == bh>>3
    const int t  = threadIdx.x;
    const int w  = t >> 6;                      // 0..7
    const int lane = t & 63;
    const int li = lane & 31;
    const int hi = lane >> 5;

    const short* Qb = qws + (size_t)bh * (Nc * Dc);
    const short* Kb = kws + (size_t)bh * (Nc * Dc);

    s16x8 qF[4];
    {
        const short* qp = Qb + (size_t)(rb * 32 + li) * Dc + hi * 8;
#pragma unroll
        for (int s = 0; s < 4; ++s)
            qF[s] = *(const s16x8*)(qp + s * 16);
    }

    f32x16 acc[4];
#pragma unroll
    for (int i = 0; i < 4; ++i) acc[i] = (f32x16)(0.f);

    const int colbase = w * 128;                // wave owns 128 cols
#pragma unroll
    for (int ct = 0; ct < 4; ++ct) {
        const short* kp = Kb + (size_t)(colbase + ct * 32 + li) * Dc + hi * 8;
#pragma unroll
        for (int s = 0; s < 4; ++s) {
            s16x8 kf = *(const s16x8*)(kp + s * 16);
            acc[ct] = __builtin_amdgcn_mfma_f32_32x32x16_bf16(qF[s], kf, acc[ct], 0, 0, 0);
        }
    }

    // exp + row partial sum (no max subtraction; scores tiny in exp2 space)
    const float c = 1.44269504f / 32.0f;   // log2(e)/SCALE, SCALE = 32
    float sm[16];
#pragma unroll
    for (int r = 0; r < 16; ++r) sm[r] = 0.f;
#pragma unroll
    for (int ct = 0; ct < 4; ++ct) {
#pragma unroll
        for (int r = 0; r < 16; ++r) {
            float p = __builtin_amdgcn_exp2f(acc[ct][r] * c);
            acc[ct][r] = p;
            sm[r] += p;
        }
    }
#pragma unroll
    for (int r = 0; r < 16; ++r) {
#pragma unroll
        for (int off = 1; off < 32; off <<= 1)
            sm[r] += __shfl_xor(sm[r], off);
    }

    __shared__ float red[8][32];
    if (li == 0) {
#pragma unroll
        for (int r = 0; r < 16; ++r)
            red[w][(r & 3) + 8 * (r >> 2) + 4 * hi] = sm[r];
    }
    __syncthreads();
#pragma unroll
    for (int r = 0; r < 16; ++r) {
        const int row = (r & 3) + 8 * (r >> 2) + 4 * hi;
        float s = red[0][row] + red[1][row] + red[2][row] + red[3][row] +
                  red[4][row] + red[5][row] + red[6][row] + red[7][row];
        sm[r] = 1.0f / s;
    }

    // NT stores (R11 A/B: NT beats cached by ~8us): full 128B-line segments
    float* outp = attnOut + (size_t)bh * (Nc * Nc) + (size_t)(rb * 32) * Nc;
#pragma unroll
    for (int ct = 0; ct < 4; ++ct) {
        const int col = colbase + ct * 32 + li;
#pragma unroll
        for (int r = 0; r < 16; ++r) {
            const int row = (r & 3) + 8 * (r >> 2) + 4 * hi;
            __builtin_nontemporal_store(acc[ct][r] * sm[r],
                                        &outp[(size_t)row * Nc + col]);
        }
    }
}

extern "C" void kernel_launch(void* const* d_in, const int* in_sizes, int n_in,
                              void* d_out, int out_size, void* d_ws, size_t ws_size,
                              hipStream_t stream) {
    const float* q  = (const float*)d_in[0];
    const float* k  = (const float*)d_in[1];
    const float* v  = (const float*)d_in[2];
    const float* Wq = (const float*)d_in[3];
    const float* bq = (const float*)d_in[4];
    const float* Wk = (const float*)d_in[5];
    const float* bk = (const float*)d_in[6];
    const float* Wv = (const float*)d_in[7];
    const float* bv = (const float*)d_in[8];

    float* out0 = (float*)d_out;                      // (B,H,N,D) fp32
    float* attn = (float*)d_out + OUT0_ELEMS;         // (B,H,N,N) fp32

    // bf16 W scratch (6 MB) in the TAIL of the attn region: read only by
    // proj_kernel, which completes before attn_kernel overwrites the region.
    short* wall = (short*)(attn + SCRATCH_OFF);       // Wq|Wk|Wv bf16

    short* qws = (short*)d_ws;                        // bf16 Q [b][h][n][d]
    short* kws = qws + (size_t)Mc * Ec;               // bf16 K [b][h][n][d]

    cvt_kernel<<<dim3(512, 3), 256, 0, stream>>>(Wq, Wk, Wv, wall);
    proj_kernel<<<dim3(32, 8, 3), 256, 0, stream>>>(
        q, k, v, wall, bq, bk, bv, qws, kws, out0);
    attn_kernel<<<2048, 512, 0, stream>>>(qws, kws, attn);
}

// Round 14
// 128.945 us; speedup vs baseline: 1.2111x; 1.2111x over previous
//
#include <hip/hip_runtime.h>
#include <hip/hip_bf16.h>
#include <math.h>

// Problem constants
#define Bc 4
#define Nc 1024
#define Ec 1024
#define Hc 16
#define Dc 64
#define Mc 4096                    // B*N rows
#define OUT0_ELEMS 4194304         // B*H*N*D
#define ATTN_ELEMS 67108864ULL     // B*H*N*N floats
#define SCRATCH_OFF 58720256       // float offset into attn region for bf16 scratch
#define NTK 32                     // K-tiles (BK=32) in proj

typedef __attribute__((ext_vector_type(4))) float f32x4;
typedef __attribute__((ext_vector_type(16))) float f32x16;
typedef __attribute__((ext_vector_type(8))) short s16x8;

// Hardware bf16 convert (compiler pairs into v_cvt_pk_bf16_f32)
__device__ __forceinline__ short f2bf(float f) {
    union { __bf16 h; short s; } c; c.h = (__bf16)f; return c.s;
}

// async global->LDS, 16B per lane; LDS dest = wave-uniform base + lane*16
typedef const __attribute__((address_space(1))) char gch;
typedef __attribute__((address_space(3))) char lch;
__device__ __forceinline__ void gload16(const short* g, short* l) {
    __builtin_amdgcn_global_load_lds((gch*)g, (lch*)l, 16, 0, 0);
}

// ---------------------------------------------------------------------------
// fp32 -> bf16 pre-pass, W matrices ONLY (12 MB read / 6 MB write, ~2us).
// X is converted in-kernel inside proj's pipeline.
// ---------------------------------------------------------------------------
__global__ __launch_bounds__(256)
void cvt_kernel(const float* __restrict__ wq, const float* __restrict__ wk,
                const float* __restrict__ wv, short* __restrict__ dst)
{
    const int which = blockIdx.y;
    const float* src = (which == 0) ? wq : (which == 1) ? wk : wv;
    const size_t off = (size_t)which * 1048576;
    const size_t i = ((size_t)blockIdx.x * 256 + threadIdx.x) * 8;
    f32x4 a = *(const f32x4*)(src + i);
    f32x4 b = *(const f32x4*)(src + i + 4);
    s16x8 o;
    o[0] = f2bf(a[0]); o[1] = f2bf(a[1]); o[2] = f2bf(a[2]); o[3] = f2bf(a[3]);
    o[4] = f2bf(b[0]); o[5] = f2bf(b[1]); o[6] = f2bf(b[2]); o[7] = f2bf(b[3]);
    *(s16x8*)(dst + off + i) = o;
}

// ---------------------------------------------------------------------------
// Projection GEMM, round-14: fp32 X reg-staged with WRITE-AHEAD double-
// buffered A (fix of R13's serialization): COMPUTE(t) reads lA[t&1] written
// at iter t-1; WRITEA for t+1 runs AFTER compute, its regs loaded at t-1.
// B (bf16 W) keeps the R7 3-buffer gload_lds rotation with vmcnt(6).
// LDS = 2x8KB (A) + 3x8KB (B) = 40 KB.
// ---------------------------------------------------------------------------
__global__ __launch_bounds__(256)
void proj_kernel(const float* __restrict__ xq, const float* __restrict__ xk,
                 const float* __restrict__ xv, const short* __restrict__ wall,
                 const float* __restrict__ bq, const float* __restrict__ bk,
                 const float* __restrict__ bv,
                 short* __restrict__ qws, short* __restrict__ kws,
                 float* __restrict__ vout)
{
    const int sel = blockIdx.z;
    const float* X = (sel == 0) ? xq : (sel == 1) ? xk : xv;
    const short* W = wall + (size_t)sel * 1048576;
    const float* bias = (sel == 0) ? bq : (sel == 1) ? bk : bv;

    __shared__ __align__(16) short lA[2][128 * 32];
    __shared__ __align__(16) short lB[3][128 * 32];

    const int t    = threadIdx.x;
    const int lane = t & 63;
    const int w    = t >> 6;
    const int wr   = w >> 1, wc = w & 1;      // 2x2 wave grid, 64x64 each
    const int li   = lane & 15, g = lane >> 4;
    const int bm   = blockIdx.x * 128;
    const int bn   = blockIdx.y * 128;

    // A staging: thread -> rows {r0, r0+64}, 8-float chunk c2 (32B).
    // Load instr = 16 rows x 64B contiguous segments. Write = 2x b128,
    // bank-minimal (each bank-quad serves exactly 8 lanes).
    const int r0 = t >> 2;                    // 0..63
    const int c2 = t & 3;                     // 8-float chunk within 32
    const float* Xa = X + (size_t)(bm + r0) * Ec + c2 * 8;
    const float* Xb = X + (size_t)(bm + r0 + 64) * Ec + c2 * 8;
    const int sw = (r0 >> 1) & 3;             // same for r0+64
    const int aoff0 = r0 * 32 + ((c2 ^ sw) * 8);
    const int aoff1 = (r0 + 64) * 32 + ((c2 ^ sw) * 8);

    // B staging (R7 mapping): 16B chunk pre-swizzled global source
    const int sr = lane >> 2;
    const int c_ = lane & 3;

    f32x4 acc[4][4];
#pragma unroll
    for (int i = 0; i < 4; ++i)
#pragma unroll
        for (int j = 0; j < 4; ++j)
            acc[i][j] = (f32x4){0.f, 0.f, 0.f, 0.f};

    f32x4 e0, e1, e2, e3;   // even-parity A reg set
    f32x4 o0, o1, o2, o3;   // odd-parity A reg set

#define LOADA(q0, q1, q2, q3, kt)                                             \
    {                                                                         \
        const float* pa = Xa + (kt) * 32;                                     \
        const float* pb = Xb + (kt) * 32;                                     \
        q0 = *(const f32x4*)(pa);                                             \
        q1 = *(const f32x4*)(pa + 4);                                         \
        q2 = *(const f32x4*)(pb);                                             \
        q3 = *(const f32x4*)(pb + 4);                                         \
    }

#define STAGEB(buf, kt)                                                       \
    {                                                                         \
        const int kb = (kt) * 32;                                             \
        _Pragma("unroll")                                                     \
        for (int j = 0; j < 2; ++j) {                                         \
            const int row = w * 32 + j * 16 + sr;                             \
            const int cg  = (c_ ^ ((row >> 1) & 3)) * 8;                      \
            gload16(W + (size_t)(bn + row) * Ec + kb + cg,                    \
                    &lB[buf][(w * 32 + j * 16) * 32]);                        \
        }                                                                     \
    }

#define WRITEA(abuf, q0, q1, q2, q3)                                          \
    {                                                                         \
        s16x8 h0, h1;                                                         \
        _Pragma("unroll")                                                     \
        for (int i = 0; i < 4; ++i) {                                         \
            h0[i] = f2bf(q0[i]); h0[i + 4] = f2bf(q1[i]);                     \
            h1[i] = f2bf(q2[i]); h1[i + 4] = f2bf(q3[i]);                     \
        }                                                                     \
        *(s16x8*)&lA[abuf][aoff0] = h0;                                       \
        *(s16x8*)&lA[abuf][aoff1] = h1;                                       \
    }

#define COMPUTE(abuf, bbuf)                                                   \
    {                                                                         \
        s16x8 aF[4], bF[4];                                                   \
        _Pragma("unroll")                                                     \
        for (int mt = 0; mt < 4; ++mt) {                                      \
            const int r = wr * 64 + mt * 16 + li;                             \
            aF[mt] = *(const s16x8*)&lA[abuf][r * 32 + ((g ^ ((r >> 1) & 3)) * 8)]; \
        }                                                                     \
        _Pragma("unroll")                                                     \
        for (int nt = 0; nt < 4; ++nt) {                                      \
            const int r = wc * 64 + nt * 16 + li;                             \
            bF[nt] = *(const s16x8*)&lB[bbuf][r * 32 + ((g ^ ((r >> 1) & 3)) * 8)]; \
        }                                                                     \
        _Pragma("unroll")                                                     \
        for (int mt = 0; mt < 4; ++mt)                                        \
            _Pragma("unroll")                                                 \
            for (int nt = 0; nt < 4; ++nt)                                    \
                acc[mt][nt] = __builtin_amdgcn_mfma_f32_16x16x32_bf16(        \
                    aF[mt], bF[nt], acc[mt][nt], 0, 0, 0);                    \
    }

    // ---- prologue: stages 0,1 in flight; lA[0] written ahead ----
    LOADA(e0, e1, e2, e3, 0);
    STAGEB(0, 0);
    LOADA(o0, o1, o2, o3, 1);
    STAGEB(1, 1);
    WRITEA(0, e0, e1, e2, e3);     // compiler auto-waits A(0) regs
    asm volatile("s_waitcnt lgkmcnt(0)" ::: "memory");

    for (int tt = 0; tt < NTK; tt += 2) {
        // ======= iter t = tt (even): lA[0], set o holds A(tt+1) =======
        asm volatile("s_waitcnt vmcnt(6)" ::: "memory");   // retire B(tt)
        __builtin_amdgcn_s_barrier();
        COMPUTE(0, tt % 3);
        WRITEA(1, o0, o1, o2, o3);                          // stage tt+1
        if (tt + 2 < NTK) {
            LOADA(e0, e1, e2, e3, tt + 2);
            STAGEB((tt + 2) % 3, tt + 2);
        }
        asm volatile("s_waitcnt lgkmcnt(0)" ::: "memory");
        __builtin_amdgcn_s_barrier();

        // ======= iter t = tt+1 (odd): lA[1], set e holds A(tt+2) =======
        if (tt + 1 < NTK - 1) {
            asm volatile("s_waitcnt vmcnt(6)" ::: "memory");
        } else {
            asm volatile("s_waitcnt vmcnt(0)" ::: "memory");
        }
        __builtin_amdgcn_s_barrier();
        COMPUTE(1, (tt + 1) % 3);
        if (tt + 2 < NTK) {
            WRITEA(0, e0, e1, e2, e3);                      // stage tt+2
            if (tt + 3 < NTK) {
                LOADA(o0, o1, o2, o3, tt + 3);
                STAGEB((tt + 3) % 3, tt + 3);
            }
        }
        asm volatile("s_waitcnt lgkmcnt(0)" ::: "memory");
        __builtin_amdgcn_s_barrier();
    }
#undef COMPUTE
#undef WRITEA
#undef STAGEB
#undef LOADA

    // ---- epilogue: bias add + head-split scatter ----
    short* dstBF = (sel == 0) ? qws : kws;
#pragma unroll
    for (int nt = 0; nt < 4; ++nt) {
        const int col = bn + wc * 64 + nt * 16 + li;
        const float bcol = bias[col];
        const int h = col >> 6, d = col & 63;
#pragma unroll
        for (int mt = 0; mt < 4; ++mt) {
#pragma unroll
            for (int r = 0; r < 4; ++r) {
                const int row = bm + wr * 64 + mt * 16 + g * 4 + r;
                const int bb = row >> 10, n = row & 1023;
                const size_t off = ((size_t)(bb * Hc + h) * Nc + n) * Dc + d;
                const float val = acc[mt][nt][r] + bcol;
                if (sel == 2)
                    vout[off] = val;
                else
                    dstBF[off] = f2bf(val);
            }
        }
    }
}

// ---------------------------------------------------------------------------
// Scores + softmax (R10 exact: 8 waves x 128 cols, no max pass, NT stores,
// XCD-clustered grid).
// ---------------------------------------------------------------------------
__global__ __launch_bounds__(512, 4)
void attn_kernel(const short* __restrict__ qws, const short* __restrict__ kws,
                 float* __restrict__ attnOut)
{
    const int bid = blockIdx.x;                 // 0..2047
    const int rb  = (bid >> 3) & 31;            // 32-row block
    const int bh  = ((bid & 7) << 3) | (bid >> 8);  // head: bid%8 == bh>>3
    const int t  = threadIdx.x;
    const int w  = t >> 6;                      // 0..7
    const int lane = t & 63;
    const int li = lane & 31;
    const int hi = lane >> 5;

    const short* Qb = qws + (size_t)bh * (Nc * Dc);
    const short* Kb = kws + (size_t)bh * (Nc * Dc);

    s16x8 qF[4];
    {
        const short* qp = Qb + (size_t)(rb * 32 + li) * Dc + hi * 8;
#pragma unroll
        for (int s = 0; s < 4; ++s)
            qF[s] = *(const s16x8*)(qp + s * 16);
    }

    f32x16 acc[4];
#pragma unroll
    for (int i = 0; i < 4; ++i) acc[i] = (f32x16)(0.f);

    const int colbase = w * 128;                // wave owns 128 cols
#pragma unroll
    for (int ct = 0; ct < 4; ++ct) {
        const short* kp = Kb + (size_t)(colbase + ct * 32 + li) * Dc + hi * 8;
#pragma unroll
        for (int s = 0; s < 4; ++s) {
            s16x8 kf = *(const s16x8*)(kp + s * 16);
            acc[ct] = __builtin_amdgcn_mfma_f32_32x32x16_bf16(qF[s], kf, acc[ct], 0, 0, 0);
        }
    }

    // exp + row partial sum (no max subtraction; scores tiny in exp2 space)
    const float c = 1.44269504f / 32.0f;   // log2(e)/SCALE, SCALE = 32
    float sm[16];
#pragma unroll
    for (int r = 0; r < 16; ++r) sm[r] = 0.f;
#pragma unroll
    for (int ct = 0; ct < 4; ++ct) {
#pragma unroll
        for (int r = 0; r < 16; ++r) {
            float p = __builtin_amdgcn_exp2f(acc[ct][r] * c);
            acc[ct][r] = p;
            sm[r] += p;
        }
    }
#pragma unroll
    for (int r = 0; r < 16; ++r) {
#pragma unroll
        for (int off = 1; off < 32; off <<= 1)
            sm[r] += __shfl_xor(sm[r], off);
    }

    __shared__ float red[8][32];
    if (li == 0) {
#pragma unroll
        for (int r = 0; r < 16; ++r)
            red[w][(r & 3) + 8 * (r >> 2) + 4 * hi] = sm[r];
    }
    __syncthreads();
#pragma unroll
    for (int r = 0; r < 16; ++r) {
        const int row = (r & 3) + 8 * (r >> 2) + 4 * hi;
        float s = red[0][row] + red[1][row] + red[2][row] + red[3][row] +
                  red[4][row] + red[5][row] + red[6][row] + red[7][row];
        sm[r] = 1.0f / s;
    }

    // NT stores (R11 A/B: NT beats cached by ~8us): full 128B-line segments
    float* outp = attnOut + (size_t)bh * (Nc * Nc) + (size_t)(rb * 32) * Nc;
#pragma unroll
    for (int ct = 0; ct < 4; ++ct) {
        const int col = colbase + ct * 32 + li;
#pragma unroll
        for (int r = 0; r < 16; ++r) {
            const int row = (r & 3) + 8 * (r >> 2) + 4 * hi;
            __builtin_nontemporal_store(acc[ct][r] * sm[r],
                                        &outp[(size_t)row * Nc + col]);
        }
    }
}

extern "C" void kernel_launch(void* const* d_in, const int* in_sizes, int n_in,
                              void* d_out, int out_size, void* d_ws, size_t ws_size,
                              hipStream_t stream) {
    const float* q  = (const float*)d_in[0];
    const float* k  = (const float*)d_in[1];
    const float* v  = (const float*)d_in[2];
    const float* Wq = (const float*)d_in[3];
    const float* bq = (const float*)d_in[4];
    const float* Wk = (const float*)d_in[5];
    const float* bk = (const float*)d_in[6];
    const float* Wv = (const float*)d_in[7];
    const float* bv = (const float*)d_in[8];

    float* out0 = (float*)d_out;                      // (B,H,N,D) fp32
    float* attn = (float*)d_out + OUT0_ELEMS;         // (B,H,N,N) fp32

    // bf16 W scratch (6 MB) in the TAIL of the attn region: read only by
    // proj_kernel, which completes before attn_kernel overwrites the region.
    short* wall = (short*)(attn + SCRATCH_OFF);       // Wq|Wk|Wv bf16

    short* qws = (short*)d_ws;                        // bf16 Q [b][h][n][d]
    short* kws = qws + (size_t)Mc * Ec;               // bf16 K [b][h][n][d]

    cvt_kernel<<<dim3(512, 3), 256, 0, stream>>>(Wq, Wk, Wv, wall);
    proj_kernel<<<dim3(32, 8, 3), 256, 0, stream>>>(
        q, k, v, wall, bq, bk, bv, qws, kws, out0);
    attn_kernel<<<2048, 512, 0, stream>>>(qws, kws, attn);
}

// Round 15
// 118.807 us; speedup vs baseline: 1.3145x; 1.0853x over previous
//
#include <hip/hip_runtime.h>
#include <hip/hip_bf16.h>
#include <math.h>

// Problem constants
#define Bc 4
#define Nc 1024
#define Ec 1024
#define Hc 16
#define Dc 64
#define Mc 4096                    // B*N rows
#define OUT0_ELEMS 4194304         // B*H*N*D
#define ATTN_ELEMS 67108864ULL     // B*H*N*N floats
#define SCRATCH_OFF 58720256       // float offset into attn region for bf16 scratch
#define NTK 32                     // K-tiles (BK=32)

typedef __attribute__((ext_vector_type(4))) float f32x4;
typedef __attribute__((ext_vector_type(16))) float f32x16;
typedef __attribute__((ext_vector_type(8))) short s16x8;

// Hardware bf16 convert (compiler pairs into v_cvt_pk_bf16_f32)
__device__ __forceinline__ short f2bf(float f) {
    union { __bf16 h; short s; } c; c.h = (__bf16)f; return c.s;
}

// async global->LDS, 16B per lane; LDS dest = wave-uniform base + lane*16
typedef const __attribute__((address_space(1))) char gch;
typedef __attribute__((address_space(3))) char lch;
__device__ __forceinline__ void gload16(const short* g, short* l) {
    __builtin_amdgcn_global_load_lds((gch*)g, (lch*)l, 16, 0, 0);
}

// ---------------------------------------------------------------------------
// fp32 -> bf16 pre-pass: Q/K inputs only (Xq, Xk, Wq, Wk). ~10us.
// ---------------------------------------------------------------------------
__global__ __launch_bounds__(256)
void cvt_kernel(const float* __restrict__ xq, const float* __restrict__ xk,
                const float* __restrict__ wq, const float* __restrict__ wk,
                short* __restrict__ dst)
{
    const int which = blockIdx.y;
    const float* src; size_t n, off;
    switch (which) {
      case 0:  src = xq; n = 4194304; off = 0;       break;
      case 1:  src = xk; n = 4194304; off = 4194304; break;
      case 2:  src = wq; n = 1048576; off = 8388608; break;
      default: src = wk; n = 1048576; off = 9437184; break;
    }
    const size_t i = ((size_t)blockIdx.x * 256 + threadIdx.x) * 8;
    if (i >= n) return;
    f32x4 a = *(const f32x4*)(src + i);
    f32x4 b = *(const f32x4*)(src + i + 4);
    s16x8 o;
    o[0] = f2bf(a[0]); o[1] = f2bf(a[1]); o[2] = f2bf(a[2]); o[3] = f2bf(a[3]);
    o[4] = f2bf(b[0]); o[5] = f2bf(b[1]); o[6] = f2bf(b[2]); o[7] = f2bf(b[3]);
    *(s16x8*)(dst + off + i) = o;
}

// ---------------------------------------------------------------------------
// Q/K projection GEMM (R7 structure, proven in R12; sel in {0,1}).
// ---------------------------------------------------------------------------
__global__ __launch_bounds__(256)
void proj_kernel(const short* __restrict__ xall, const short* __restrict__ wall,
                 const float* __restrict__ bq, const float* __restrict__ bk,
                 short* __restrict__ qws, short* __restrict__ kws)
{
    const int sel = blockIdx.z;
    const short* X = xall + (size_t)sel * 4194304;
    const short* W = wall + (size_t)sel * 1048576;
    const float* bias = (sel == 0) ? bq : bk;

    __shared__ __align__(16) short lA[3][128 * 32];
    __shared__ __align__(16) short lB[3][128 * 32];

    const int t    = threadIdx.x;
    const int lane = t & 63;
    const int w    = t >> 6;
    const int wr   = w >> 1, wc = w & 1;      // 2x2 wave grid, 64x64 each
    const int li   = lane & 15, g = lane >> 4;
    const int bm   = blockIdx.x * 128;
    const int bn   = blockIdx.y * 128;

    const int sr = lane >> 2;
    const int c_ = lane & 3;

    f32x4 acc[4][4];
#pragma unroll
    for (int i = 0; i < 4; ++i)
#pragma unroll
        for (int j = 0; j < 4; ++j)
            acc[i][j] = (f32x4){0.f, 0.f, 0.f, 0.f};

#define STAGE(buf, kt)                                                        \
    {                                                                         \
        const int kb = (kt) * 32;                                             \
        _Pragma("unroll")                                                     \
        for (int j = 0; j < 2; ++j) {                                         \
            const int row = w * 32 + j * 16 + sr;                             \
            const int cg  = (c_ ^ ((row >> 1) & 3)) * 8;                      \
            gload16(X + (size_t)(bm + row) * Ec + kb + cg,                    \
                    &lA[buf][(w * 32 + j * 16) * 32]);                        \
            gload16(W + (size_t)(bn + row) * Ec + kb + cg,                    \
                    &lB[buf][(w * 32 + j * 16) * 32]);                        \
        }                                                                     \
    }

    STAGE(0, 0);
    STAGE(1, 1);
    asm volatile("s_waitcnt vmcnt(4)" ::: "memory");
    __builtin_amdgcn_s_barrier();

    for (int kt = 0; kt < NTK; ++kt) {
        const int cur = kt % 3;
        if (kt + 2 < NTK) STAGE((kt + 2) % 3, kt + 2);

        s16x8 aF[4], bF[4];
#pragma unroll
        for (int mt = 0; mt < 4; ++mt) {
            const int r = wr * 64 + mt * 16 + li;
            aF[mt] = *(const s16x8*)&lA[cur][r * 32 + ((g ^ ((r >> 1) & 3)) * 8)];
        }
#pragma unroll
        for (int nt = 0; nt < 4; ++nt) {
            const int r = wc * 64 + nt * 16 + li;
            bF[nt] = *(const s16x8*)&lB[cur][r * 32 + ((g ^ ((r >> 1) & 3)) * 8)];
        }
#pragma unroll
        for (int mt = 0; mt < 4; ++mt)
#pragma unroll
            for (int nt = 0; nt < 4; ++nt)
                acc[mt][nt] = __builtin_amdgcn_mfma_f32_16x16x32_bf16(
                    aF[mt], bF[nt], acc[mt][nt], 0, 0, 0);

        if (kt + 2 < NTK) {
            asm volatile("s_waitcnt vmcnt(4)" ::: "memory");
        } else {
            asm volatile("s_waitcnt vmcnt(0)" ::: "memory");
        }
        __builtin_amdgcn_s_barrier();
    }
#undef STAGE

    short* dstBF = (sel == 0) ? qws : kws;
#pragma unroll
    for (int nt = 0; nt < 4; ++nt) {
        const int col = bn + wc * 64 + nt * 16 + li;
        const float bcol = bias[col];
        const int h = col >> 6, d = col & 63;
#pragma unroll
        for (int mt = 0; mt < 4; ++mt) {
#pragma unroll
            for (int r = 0; r < 4; ++r) {
                const int row = bm + wr * 64 + mt * 16 + g * 4 + r;
                const int bb = row >> 10, n = row & 1023;
                const size_t off = ((size_t)(bb * Hc + h) * Nc + n) * Dc + d;
                dstBF[off] = f2bf(acc[mt][nt][r] + bcol);
            }
        }
    }
}

// ---------------------------------------------------------------------------
// Fused kernel:
//   bid <  256 -> V-projection, R14 write-ahead structure: both operands
//                 reg-staged fp32->bf16 (reads ORIGINAL v/Wv, no scratch
//                 dependency -> no race), 2x(A+B) LDS double buffer, 8 waves
//                 in 2Mx4N grid (64x32/wave). Hides under attn's store drain.
//   bid >= 256 -> scores+softmax (R10 exact: 8 waves x 128 cols, no max
//                 pass, NT stores, XCD-clustered).
// ---------------------------------------------------------------------------
__global__ __launch_bounds__(512, 4)
void fused_kernel(const short* __restrict__ qws, const short* __restrict__ kws,
                  float* __restrict__ attnOut,
                  const float* __restrict__ vin, const float* __restrict__ Wv,
                  const float* __restrict__ bv, float* __restrict__ out0)
{
    __shared__ __align__(16) short lsA[2][128 * 32];
    __shared__ __align__(16) short lsB[2][128 * 32];
    __shared__ float red[8][32];

    const int bid = blockIdx.x;
    const int t   = threadIdx.x;
    const int lane = t & 63;

    if (bid < 256) {
        // ============ V-projection: 128x128 tile, write-ahead dbuf ========
        const int bm = (bid & 31) * 128;
        const int bn = (bid >> 5) * 128;
        const int w  = t >> 6;
        const int wr = w >> 2;               // 0..1: 64-row half
        const int wc = w & 3;                // 0..3: 32-col quarter
        const int li = lane & 15, g = lane >> 4;

        // staging: thread -> row r0 (0..127), 16B chunk c2 (0..3)
        const int r0 = t >> 2;
        const int c2 = t & 3;
        const float* Xs = vin + (size_t)(bm + r0) * Ec + c2 * 8;
        const float* Ws = Wv  + (size_t)(bn + r0) * Ec + c2 * 8;
        const int aoff = r0 * 32 + ((c2 ^ ((r0 >> 1) & 3)) * 8);

        f32x4 acc[4][2];
#pragma unroll
        for (int i = 0; i < 4; ++i)
#pragma unroll
            for (int j = 0; j < 2; ++j)
                acc[i][j] = (f32x4){0.f, 0.f, 0.f, 0.f};

        f32x4 eA0, eA1, eB0, eB1;   // even-parity staging regs
        f32x4 oA0, oA1, oB0, oB1;   // odd-parity staging regs

#define VLOAD(a0, a1, b0, b1, kt)                                             \
        {                                                                     \
            const float* pa = Xs + (kt) * 32;                                 \
            const float* pb = Ws + (kt) * 32;                                 \
            a0 = *(const f32x4*)(pa); a1 = *(const f32x4*)(pa + 4);           \
            b0 = *(const f32x4*)(pb); b1 = *(const f32x4*)(pb + 4);           \
        }

#define VWRITE(buf, a0, a1, b0, b1)                                           \
        {                                                                     \
            s16x8 ha, hb;                                                     \
            _Pragma("unroll")                                                 \
            for (int i = 0; i < 4; ++i) {                                     \
                ha[i] = f2bf(a0[i]); ha[i + 4] = f2bf(a1[i]);                 \
                hb[i] = f2bf(b0[i]); hb[i + 4] = f2bf(b1[i]);                 \
            }                                                                 \
            *(s16x8*)&lsA[buf][aoff] = ha;                                    \
            *(s16x8*)&lsB[buf][aoff] = hb;                                    \
        }

#define VCOMPUTE(buf)                                                         \
        {                                                                     \
            s16x8 aF[4], bF[2];                                               \
            _Pragma("unroll")                                                 \
            for (int mt = 0; mt < 4; ++mt) {                                  \
                const int r = wr * 64 + mt * 16 + li;                         \
                aF[mt] = *(const s16x8*)&lsA[buf][r * 32 + ((g ^ ((r >> 1) & 3)) * 8)]; \
            }                                                                 \
            _Pragma("unroll")                                                 \
            for (int nt = 0; nt < 2; ++nt) {                                  \
                const int r = wc * 32 + nt * 16 + li;                         \
                bF[nt] = *(const s16x8*)&lsB[buf][r * 32 + ((g ^ ((r >> 1) & 3)) * 8)]; \
            }                                                                 \
            _Pragma("unroll")                                                 \
            for (int mt = 0; mt < 4; ++mt)                                    \
                _Pragma("unroll")                                             \
                for (int nt = 0; nt < 2; ++nt)                                \
                    acc[mt][nt] = __builtin_amdgcn_mfma_f32_16x16x32_bf16(    \
                        aF[mt], bF[nt], acc[mt][nt], 0, 0, 0);                \
        }

        // prologue: k0 in lds0; k1,k2 regs in flight
        VLOAD(eA0, eA1, eB0, eB1, 0);
        VLOAD(oA0, oA1, oB0, oB1, 1);
        VWRITE(0, eA0, eA1, eB0, eB1);      // compiler waits k0 regs
        VLOAD(eA0, eA1, eB0, eB1, 2);
        asm volatile("s_waitcnt lgkmcnt(0)" ::: "memory");
        __builtin_amdgcn_s_barrier();

        for (int tt = 0; tt < NTK; tt += 2) {
            // iter tt (even): compute lds0; write k=tt+1 (odd regs) to lds1
            VCOMPUTE(0);
            if (tt + 1 < NTK) {
                VWRITE(1, oA0, oA1, oB0, oB1);
                if (tt + 3 < NTK) VLOAD(oA0, oA1, oB0, oB1, tt + 3);
            }
            asm volatile("s_waitcnt lgkmcnt(0)" ::: "memory");
            __builtin_amdgcn_s_barrier();

            // iter tt+1 (odd): compute lds1; write k=tt+2 (even regs) to lds0
            if (tt + 1 < NTK) {
                VCOMPUTE(1);
                if (tt + 2 < NTK) {
                    VWRITE(0, eA0, eA1, eB0, eB1);
                    if (tt + 4 < NTK) VLOAD(eA0, eA1, eB0, eB1, tt + 4);
                }
                asm volatile("s_waitcnt lgkmcnt(0)" ::: "memory");
                __builtin_amdgcn_s_barrier();
            }
        }
#undef VCOMPUTE
#undef VWRITE
#undef VLOAD

        // epilogue: bias + head-split scatter (fp32 to out0)
#pragma unroll
        for (int nt = 0; nt < 2; ++nt) {
            const int col = bn + wc * 32 + nt * 16 + li;
            const float bcol = bv[col];
            const int h = col >> 6, d = col & 63;
#pragma unroll
            for (int mt = 0; mt < 4; ++mt) {
#pragma unroll
                for (int r = 0; r < 4; ++r) {
                    const int row = bm + wr * 64 + mt * 16 + g * 4 + r;
                    const int bb = row >> 10, n = row & 1023;
                    out0[((size_t)(bb * Hc + h) * Nc + n) * Dc + d] =
                        acc[mt][nt][r] + bcol;
                }
            }
        }
        return;
    }

    // ===================== attn: scores + softmax (R10) ====================
    const int abid = bid - 256;                 // 0..2047
    const int rb  = (abid >> 3) & 31;           // 32-row block
    const int bh  = ((abid & 7) << 3) | (abid >> 8);  // head: abid%8 == bh>>3
    const int w  = t >> 6;                      // 0..7
    const int li = lane & 31;
    const int hi = lane >> 5;

    const short* Qb = qws + (size_t)bh * (Nc * Dc);
    const short* Kb = kws + (size_t)bh * (Nc * Dc);

    s16x8 qF[4];
    {
        const short* qp = Qb + (size_t)(rb * 32 + li) * Dc + hi * 8;
#pragma unroll
        for (int s = 0; s < 4; ++s)
            qF[s] = *(const s16x8*)(qp + s * 16);
    }

    f32x16 acc[4];
#pragma unroll
    for (int i = 0; i < 4; ++i) acc[i] = (f32x16)(0.f);

    const int colbase = w * 128;                // wave owns 128 cols
#pragma unroll
    for (int ct = 0; ct < 4; ++ct) {
        const short* kp = Kb + (size_t)(colbase + ct * 32 + li) * Dc + hi * 8;
#pragma unroll
        for (int s = 0; s < 4; ++s) {
            s16x8 kf = *(const s16x8*)(kp + s * 16);
            acc[ct] = __builtin_amdgcn_mfma_f32_32x32x16_bf16(qF[s], kf, acc[ct], 0, 0, 0);
        }
    }

    // exp + row partial sum (no max subtraction; scores tiny in exp2 space)
    const float c = 1.44269504f / 32.0f;   // log2(e)/SCALE, SCALE = 32
    float sm[16];
#pragma unroll
    for (int r = 0; r < 16; ++r) sm[r] = 0.f;
#pragma unroll
    for (int ct = 0; ct < 4; ++ct) {
#pragma unroll
        for (int r = 0; r < 16; ++r) {
            float p = __builtin_amdgcn_exp2f(acc[ct][r] * c);
            acc[ct][r] = p;
            sm[r] += p;
        }
    }
#pragma unroll
    for (int r = 0; r < 16; ++r) {
#pragma unroll
        for (int off = 1; off < 32; off <<= 1)
            sm[r] += __shfl_xor(sm[r], off);
    }

    if (li == 0) {
#pragma unroll
        for (int r = 0; r < 16; ++r)
            red[w][(r & 3) + 8 * (r >> 2) + 4 * hi] = sm[r];
    }
    __syncthreads();
#pragma unroll
    for (int r = 0; r < 16; ++r) {
        const int row = (r & 3) + 8 * (r >> 2) + 4 * hi;
        float s = red[0][row] + red[1][row] + red[2][row] + red[3][row] +
                  red[4][row] + red[5][row] + red[6][row] + red[7][row];
        sm[r] = 1.0f / s;
    }

    // NT stores (R11 A/B: NT beats cached by ~8us): full 128B-line segments
    float* outp = attnOut + (size_t)bh * (Nc * Nc) + (size_t)(rb * 32) * Nc;
#pragma unroll
    for (int ct = 0; ct < 4; ++ct) {
        const int col = colbase + ct * 32 + li;
#pragma unroll
        for (int r = 0; r < 16; ++r) {
            const int row = (r & 3) + 8 * (r >> 2) + 4 * hi;
            __builtin_nontemporal_store(acc[ct][r] * sm[r],
                                        &outp[(size_t)row * Nc + col]);
        }
    }
}

extern "C" void kernel_launch(void* const* d_in, const int* in_sizes, int n_in,
                              void* d_out, int out_size, void* d_ws, size_t ws_size,
                              hipStream_t stream) {
    const float* q  = (const float*)d_in[0];
    const float* k  = (const float*)d_in[1];
    const float* v  = (const float*)d_in[2];
    const float* Wq = (const float*)d_in[3];
    const float* bq = (const float*)d_in[4];
    const float* Wk = (const float*)d_in[5];
    const float* bk = (const float*)d_in[6];
    const float* Wv = (const float*)d_in[7];
    const float* bv = (const float*)d_in[8];

    float* out0 = (float*)d_out;                      // (B,H,N,D) fp32
    float* attn = (float*)d_out + OUT0_ELEMS;         // (B,H,N,N) fp32

    // bf16 Q/K scratch (20 MB) in the TAIL of the attn region: read only by
    // proj_kernel, which completes before the fused kernel; fused attn
    // blocks then freely overwrite it. V path reads only original inputs.
    short* s16  = (short*)(attn + SCRATCH_OFF);
    short* xall = s16;                                // Xq|Xk bf16
    short* wall = s16 + 8388608;                      // Wq|Wk bf16

    short* qws = (short*)d_ws;                        // bf16 Q [b][h][n][d]
    short* kws = qws + (size_t)Mc * Ec;               // bf16 K [b][h][n][d]

    cvt_kernel<<<dim3(2048, 4), 256, 0, stream>>>(q, k, Wq, Wk, s16);
    proj_kernel<<<dim3(32, 8, 2), 256, 0, stream>>>(
        xall, wall, bq, bk, qws, kws);
    fused_kernel<<<2304, 512, 0, stream>>>(qws, kws, attn, v, Wv, bv, out0);
}